// Round 1
// baseline (168.641 us; speedup 1.0000x reference)
//
#include <hip/hip_runtime.h>

#define BLOCK 512
#define WAVES_PER_BLOCK (BLOCK / 64)

// ---- cross-lane xor-shuffle within 16-lane rows ----
template<int CTRL>
__device__ __forceinline__ float dpp_f(float v) {
  return __int_as_float(__builtin_amdgcn_update_dpp(
      0, __float_as_int(v), CTRL, 0xF, 0xF, true));
}

template<int MASK>
__device__ __forceinline__ float shx(float v) {
  if constexpr (MASK == 1)      return dpp_f<0xB1>(v);   // quad_perm [1,0,3,2]
  else if constexpr (MASK == 2) return dpp_f<0x4E>(v);   // quad_perm [2,3,0,1]
  else if constexpr (MASK == 8) return dpp_f<0x128>(v);  // row_ror:8 (== xor 8 within row16)
  else  // MASK == 4: ds_swizzle BitMode xor=4, and=0x1F
    return __int_as_float(__builtin_amdgcn_ds_swizzle(__float_as_int(v), 0x101F));
}

// ---- gate helpers (fully unrolled, constant indices -> registers) ----
template<int MASK>
__device__ __forceinline__ void rx_cross(float (&are)[16], float (&aim)[16], float c, float s) {
#pragma unroll
  for (int r = 0; r < 16; ++r) {
    float pre = shx<MASK>(are[r]);
    float pim = shx<MASK>(aim[r]);
    float nre = __builtin_fmaf(c, are[r],  s * pim);
    float nim = __builtin_fmaf(c, aim[r], -s * pre);
    are[r] = nre; aim[r] = nim;
  }
}

template<int RM>
__device__ __forceinline__ void rx_local(float (&are)[16], float (&aim)[16], float c, float s) {
#pragma unroll
  for (int r = 0; r < 16; ++r) {
    if (!(r & RM)) {
      const int r1 = r | RM;
      float a0re = are[r],  a0im = aim[r];
      float a1re = are[r1], a1im = aim[r1];
      are[r]  = __builtin_fmaf(c, a0re,  s * a1im);
      aim[r]  = __builtin_fmaf(c, a0im, -s * a1re);
      are[r1] = __builtin_fmaf(c, a1re,  s * a0im);
      aim[r1] = __builtin_fmaf(c, a1im, -s * a0re);
    }
  }
}

template<int MASK>
__device__ __forceinline__ void cnot_cross(float (&are)[16], float (&aim)[16], bool ctrl) {
#pragma unroll
  for (int r = 0; r < 16; ++r) {
    float pre = shx<MASK>(are[r]);
    float pim = shx<MASK>(aim[r]);
    are[r] = ctrl ? pre : are[r];
    aim[r] = ctrl ? pim : aim[r];
  }
}

__device__ __forceinline__ void swap_f(float& a, float& b) { float t = a; a = b; b = t; }

__global__ __launch_bounds__(BLOCK) void qcnn_kernel(
    const float* __restrict__ x,   const float* __restrict__ fcw,
    const float* __restrict__ fcb, const float* __restrict__ qp,
    const float* __restrict__ pw,  const float* __restrict__ pb,
    float* __restrict__ out)
{
  __shared__ float s_fcw[8 * 512];   // [q][e]
  __shared__ float s_pwt[8 * 512];   // transposed: [q][o]
  __shared__ float s_pb[512];
  __shared__ float s_gc[3][8];
  __shared__ float s_gs[3][8];
  __shared__ float s_fcb[8];

  const int tid = threadIdx.x;

  // ---- stage weights ----
#pragma unroll
  for (int i = tid; i < 1024; i += BLOCK)
    ((float4*)s_fcw)[i] = ((const float4*)fcw)[i];
#pragma unroll
  for (int i = tid; i < 4096; i += BLOCK) {
    const int q = i >> 9, o = i & 511;
    s_pwt[i] = pw[o * 8 + q];
  }
  if (tid < 128) ((float4*)s_pb)[tid] = ((const float4*)pb)[tid];
  if (tid < 8)  s_fcb[tid] = fcb[tid];
  if (tid < 24) {
    const float h = 0.5f * qp[tid];
    s_gc[tid >> 3][tid & 7] = __cosf(h);
    s_gs[tid >> 3][tid & 7] = __sinf(h);
  }
  __syncthreads();

  const int wave = tid >> 6;
  const int lane = tid & 63;
  const int u = lane & 15;        // sub-lane within sample (amp bits 7..4)
  const int g = lane >> 4;        // sample-in-wave
  const int quad = blockIdx.x * WAVES_PER_BLOCK + wave;
  const int smp  = quad * 4 + g;

  // ---- Phase A: angles theta_q = x . fc_w[q] + fc_b[q] ----
  const float* xrow = x + (size_t)smp * 512;
  float acc[8];
#pragma unroll
  for (int q = 0; q < 8; ++q) acc[q] = 0.f;
#pragma unroll
  for (int t = 0; t < 8; ++t) {
    const float4 xv = *(const float4*)(xrow + u * 4 + t * 64);
#pragma unroll
    for (int q = 0; q < 8; ++q) {
      const float4 wv = *(const float4*)(s_fcw + q * 512 + u * 4 + t * 64);
      acc[q] += xv.x * wv.x + xv.y * wv.y + xv.z * wv.z + xv.w * wv.w;
    }
  }
#pragma unroll
  for (int q = 0; q < 8; ++q) {
    float a = acc[q];
    a += shx<1>(a); a += shx<2>(a); a += shx<4>(a); a += shx<8>(a);
    acc[q] = a + s_fcb[q];
  }

  float cs[8], sn[8];
#pragma unroll
  for (int q = 0; q < 8; ++q) {
    const float h = 0.5f * acc[q];
    cs[q] = __cosf(h);
    sn[q] = __sinf(h);
  }

  // ---- Phase B: RY product state. qubit0..3 <-> u3..u0, qubit4..7 <-> r3..r0 ----
  const float P = ((u & 8) ? sn[0] : cs[0]) * ((u & 4) ? sn[1] : cs[1]) *
                  ((u & 2) ? sn[2] : cs[2]) * ((u & 1) ? sn[3] : cs[3]);
  float are[16], aim[16];
#pragma unroll
  for (int r = 0; r < 16; ++r) {
    const float f = ((r & 8) ? sn[4] : cs[4]) * ((r & 4) ? sn[5] : cs[5]) *
                    ((r & 2) ? sn[6] : cs[6]) * ((r & 1) ? sn[7] : cs[7]);
    are[r] = P * f;
    aim[r] = 0.f;
  }

  // ---- Phase C: 3 layers of RX + CNOT ring ----
  const bool cn01 = (u & 8) != 0;  // CNOT(0,1) ctrl = qubit0 = u3
  const bool cn12 = (u & 4) != 0;
  const bool cn23 = (u & 2) != 0;
  const bool cn34 = (u & 1) != 0;  // CNOT(3,4) ctrl = qubit3 = u0
#pragma unroll
  for (int l = 0; l < 3; ++l) {
    float gc[8], gs[8];
#pragma unroll
    for (int q = 0; q < 8; ++q) { gc[q] = s_gc[l][q]; gs[q] = s_gs[l][q]; }
    // RX on all 8 qubits (commute; order free)
    rx_cross<8>(are, aim, gc[0], gs[0]);   // qubit0 (u3)
    rx_cross<4>(are, aim, gc[1], gs[1]);   // qubit1 (u2)
    rx_cross<2>(are, aim, gc[2], gs[2]);   // qubit2 (u1)
    rx_cross<1>(are, aim, gc[3], gs[3]);   // qubit3 (u0)
    rx_local<8>(are, aim, gc[4], gs[4]);   // qubit4 (r3)
    rx_local<4>(are, aim, gc[5], gs[5]);   // qubit5 (r2)
    rx_local<2>(are, aim, gc[6], gs[6]);   // qubit6 (r1)
    rx_local<1>(are, aim, gc[7], gs[7]);   // qubit7 (r0)
    // CNOT ring, exact order
    cnot_cross<4>(are, aim, cn01);         // (0,1): tgt u2
    cnot_cross<2>(are, aim, cn12);         // (1,2): tgt u1
    cnot_cross<1>(are, aim, cn23);         // (2,3): tgt u0
    // (3,4): ctrl u0, tgt r3 -> conditional in-register swap r <-> r+8
#pragma unroll
    for (int r = 0; r < 8; ++r) {
      float t0 = cn34 ? are[r + 8] : are[r];
      float t1 = cn34 ? are[r]     : are[r + 8];
      are[r] = t0; are[r + 8] = t1;
      float t2 = cn34 ? aim[r + 8] : aim[r];
      float t3 = cn34 ? aim[r]     : aim[r + 8];
      aim[r] = t2; aim[r + 8] = t3;
    }
    // (4,5): ctrl r3, tgt r2 -> static rename (free)
    swap_f(are[8], are[12]);  swap_f(are[9], are[13]);  swap_f(are[10], are[14]); swap_f(are[11], are[15]);
    swap_f(aim[8], aim[12]);  swap_f(aim[9], aim[13]);  swap_f(aim[10], aim[14]); swap_f(aim[11], aim[15]);
    // (5,6): ctrl r2, tgt r1
    swap_f(are[4], are[6]);   swap_f(are[5], are[7]);   swap_f(are[12], are[14]); swap_f(are[13], are[15]);
    swap_f(aim[4], aim[6]);   swap_f(aim[5], aim[7]);   swap_f(aim[12], aim[14]); swap_f(aim[13], aim[15]);
    // (6,7): ctrl r1, tgt r0
    swap_f(are[2], are[3]);   swap_f(are[6], are[7]);   swap_f(are[10], are[11]); swap_f(are[14], are[15]);
    swap_f(aim[2], aim[3]);   swap_f(aim[6], aim[7]);   swap_f(aim[10], aim[11]); swap_f(aim[14], aim[15]);
    // (7,0): ctrl r0 (odd regs), tgt qubit0 = u3 -> unconditional xor-8 permute of odd regs
#pragma unroll
    for (int r = 1; r < 16; r += 2) {
      are[r] = shx<8>(are[r]);
      aim[r] = shx<8>(aim[r]);
    }
  }

  // ---- Phase D: measure <Z_q> ----
  float p[16];
#pragma unroll
  for (int r = 0; r < 16; ++r) p[r] = are[r] * are[r] + aim[r] * aim[r];
  float e0[8], d7 = 0.f;
#pragma unroll
  for (int k = 0; k < 8; ++k) { e0[k] = p[2*k] + p[2*k+1]; d7 += p[2*k] - p[2*k+1]; }
  float e1[4], d6 = 0.f;
#pragma unroll
  for (int k = 0; k < 4; ++k) { e1[k] = e0[2*k] + e0[2*k+1]; d6 += e0[2*k] - e0[2*k+1]; }
  float e2[2], d5 = 0.f;
#pragma unroll
  for (int k = 0; k < 2; ++k) { e2[k] = e1[2*k] + e1[2*k+1]; d5 += e1[2*k] - e1[2*k+1]; }
  float S  = e2[0] + e2[1];
  float d4 = e2[0] - e2[1];

  float t;
  t = shx<1>(S);  float d3 = S - t;  S += t;
  d4 += shx<1>(d4); d5 += shx<1>(d5); d6 += shx<1>(d6); d7 += shx<1>(d7);
  t = shx<2>(S);  float d2 = S - t;  S += t;
  d3 += shx<2>(d3); d4 += shx<2>(d4); d5 += shx<2>(d5); d6 += shx<2>(d6); d7 += shx<2>(d7);
  t = shx<4>(S);  float d1 = S - t;  S += t;
  d2 += shx<4>(d2); d3 += shx<4>(d3); d4 += shx<4>(d4); d5 += shx<4>(d5); d6 += shx<4>(d6); d7 += shx<4>(d7);
  t = shx<8>(S);  float d0 = S - t;  S += t;
  d1 += shx<8>(d1); d2 += shx<8>(d2); d3 += shx<8>(d3); d4 += shx<8>(d4); d5 += shx<8>(d5); d6 += shx<8>(d6); d7 += shx<8>(d7);

  float z[8];
  z[0] = (u & 8) ? -d0 : d0;   // diff computed at stage mask8: lanes with u3=1 hold negated value
  z[1] = (u & 4) ? -d1 : d1;
  z[2] = (u & 2) ? -d2 : d2;
  z[3] = (u & 1) ? -d3 : d3;
  z[4] = d4; z[5] = d5; z[6] = d6; z[7] = d7;

  // ---- Phase E: out = z @ post_w^T + post_b ----
  float* orow = out + (size_t)smp * 512;
#pragma unroll
  for (int tt = 0; tt < 8; ++tt) {
    const int o = u * 4 + tt * 64;
    float4 r4 = *(const float4*)(s_pb + o);
#pragma unroll
    for (int q = 0; q < 8; ++q) {
      const float4 wv = *(const float4*)(s_pwt + q * 512 + o);
      const float zq = z[q];
      r4.x += zq * wv.x; r4.y += zq * wv.y; r4.z += zq * wv.z; r4.w += zq * wv.w;
    }
    *(float4*)(orow + o) = r4;
  }
}

extern "C" void kernel_launch(void* const* d_in, const int* in_sizes, int n_in,
                              void* d_out, int out_size, void* d_ws, size_t ws_size,
                              hipStream_t stream) {
  const float* x   = (const float*)d_in[0];
  const float* fcw = (const float*)d_in[1];
  const float* fcb = (const float*)d_in[2];
  const float* qp  = (const float*)d_in[3];
  const float* pw  = (const float*)d_in[4];
  const float* pb  = (const float*)d_in[5];
  float* out = (float*)d_out;

  // 32768 samples / (4 per wave * 8 waves per block) = 1024 blocks
  dim3 grid(1024), block(BLOCK);
  hipLaunchKernelGGL(qcnn_kernel, grid, block, 0, stream, x, fcw, fcb, qp, pw, pb, out);
}